// Round 1
// baseline (135.441 us; speedup 1.0000x reference)
//
#include <hip/hip_runtime.h>

// Problem constants (reference: B=4, C=64, H=512, W=512)
#define B_   4
#define C_   64
#define H_   512
#define W_   512
#define HW_  (H_ * W_)
#define TP   128          // pixels per block (row segment)
#define NBW  (W_ / TP)    // 4 segments per row

__device__ __forceinline__ void load_lds16(const float* g, float* l) {
    __builtin_amdgcn_global_load_lds(
        (const __attribute__((address_space(1))) void*)g,
        (__attribute__((address_space(3))) void*)l, 16, 0, 0);
}

// Tiny helper: W[o][c] -> WT[c][o] (4096 floats) so the main kernel's LDS
// staging is a linear copy (global_load_lds needs linear lane-order dest).
__global__ __launch_bounds__(256) void transpose_w_kernel(
    const float* __restrict__ w, float* __restrict__ wt) {
    int i = blockIdx.x * 256 + threadIdx.x;   // 0..4095
    int o = i >> 6, c = i & 63;
    wt[c * 64 + o] = w[i];
}

// Main kernel: out[b,o,h,w] = sum_c W[o][c] * x[b,c,h-1,w] + bias[o]
// (x row shifted down by one; h==0 -> bias only)
template <bool PRE_T>
__global__ __launch_bounds__(256, 3) void shift_pw_kernel(
    const float* __restrict__ x,
    const float* __restrict__ wsrc,   // PRE_T ? WT[c][o] : W[o][c]
    const float* __restrict__ bias,
    float* __restrict__ out) {

    __shared__ float xs[C_][TP];   // 32 KiB, x tile (row h-1)
    __shared__ float ws[C_][C_];   // 16 KiB, W^T: ws[c][o]

    const int tid  = threadIdx.x;
    const int lane = tid & 63;
    const int wv   = tid >> 6;

    int blk = blockIdx.x;
    const int wblk = blk & (NBW - 1);
    blk >>= 2;                     // / NBW
    const int h = blk & (H_ - 1);
    const int b = blk >> 9;        // / H_
    const int w0 = wblk * TP;

    float* xsf = &xs[0][0];
    float* wsf = &ws[0][0];

    // ---- stage W^T (4096 floats) ----
    if constexpr (PRE_T) {
        #pragma unroll
        for (int r = 0; r < 4; ++r) {
            int e = r * 1024 + wv * 256;           // wave-uniform base
            load_lds16(wsrc + e + lane * 4, wsf + e);
        }
    } else {
        // fallback (no workspace): transposing scalar writes, one-time cost
        for (int i = tid; i < C_ * C_; i += 256) {
            int o = i >> 6, c = i & 63;
            ws[c][o] = wsrc[i];
        }
    }

    // ---- stage x row (h-1), all 64 channels x 128 pixels ----
    if (h > 0) {
        const float* src = x + ((size_t)b * C_) * HW_ + (size_t)(h - 1) * W_ + w0;
        #pragma unroll
        for (int r = 0; r < 8; ++r) {
            int e  = r * 1024 + wv * 256;          // float index into xs (wave-uniform)
            int el = e + lane * 4;                 // this lane's element
            int c  = el >> 7;                      // / TP
            int p  = el & (TP - 1);
            load_lds16(src + (size_t)c * HW_ + p, xsf + e);
        }
    } else {
        float4 z = make_float4(0.f, 0.f, 0.f, 0.f);
        for (int i = tid; i < C_ * TP / 4; i += 256)
            ((float4*)xsf)[i] = z;
    }

    // ---- per-thread 8(o) x 4(pixel) register tile ----
    const int og = tid >> 5;        // 0..7  -> output channels og*8..og*8+7
    const int pg = tid & 31;        // 0..31 -> pixels pg*4..pg*4+3
    const int ob = og * 8;

    float acc[8][4];
    #pragma unroll
    for (int oo = 0; oo < 8; ++oo) {
        float bv = bias[ob + oo];
        acc[oo][0] = bv; acc[oo][1] = bv; acc[oo][2] = bv; acc[oo][3] = bv;
    }

    __syncthreads();   // drains global_load_lds (vmcnt) + LDS writes

    #pragma unroll 4
    for (int c = 0; c < C_; ++c) {
        const float4 xv = *(const float4*)&xs[c][pg * 4];    // lane-stride 16B: conflict-free
        const float4 wa = *(const float4*)&ws[c][ob];        // broadcast within half-wave
        const float4 wb = *(const float4*)&ws[c][ob + 4];
        const float xr[4] = {xv.x, xv.y, xv.z, xv.w};
        const float wr[8] = {wa.x, wa.y, wa.z, wa.w, wb.x, wb.y, wb.z, wb.w};
        #pragma unroll
        for (int oo = 0; oo < 8; ++oo)
            #pragma unroll
            for (int j = 0; j < 4; ++j)
                acc[oo][j] = fmaf(wr[oo], xr[j], acc[oo][j]);
    }

    // ---- coalesced float4 stores, each output written exactly once ----
    float* dst = out + ((size_t)b * C_) * HW_ + (size_t)h * W_ + w0 + pg * 4;
    #pragma unroll
    for (int oo = 0; oo < 8; ++oo) {
        float4 v = make_float4(acc[oo][0], acc[oo][1], acc[oo][2], acc[oo][3]);
        *(float4*)(dst + (size_t)(ob + oo) * HW_) = v;
    }
}

extern "C" void kernel_launch(void* const* d_in, const int* in_sizes, int n_in,
                              void* d_out, int out_size, void* d_ws, size_t ws_size,
                              hipStream_t stream) {
    const float* x    = (const float*)d_in[0];   // [4,64,512,512]
    const float* w    = (const float*)d_in[1];   // [64,64]
    const float* bias = (const float*)d_in[2];   // [64]
    float* out = (float*)d_out;

    const int grid = B_ * H_ * NBW;              // 8192 blocks

    if (ws_size >= C_ * C_ * sizeof(float)) {
        float* wt = (float*)d_ws;
        transpose_w_kernel<<<16, 256, 0, stream>>>(w, wt);
        shift_pw_kernel<true><<<grid, 256, 0, stream>>>(x, wt, bias, out);
    } else {
        shift_pw_kernel<false><<<grid, 256, 0, stream>>>(x, w, bias, out);
    }
}

// Round 2
// 124.402 us; speedup vs baseline: 1.0887x; 1.0887x over previous
//
#include <hip/hip_runtime.h>

// Problem constants (reference: B=4, C=64, H=512, W=512)
#define B_   4
#define C_   64
#define H_   512
#define W_   512
#define HW_  (H_ * W_)
#define TP   256          // pixels per block (row segment)
#define NBW  (W_ / TP)    // 2 segments per row

__device__ __forceinline__ void load_lds16(const float* g, float* l) {
    __builtin_amdgcn_global_load_lds(
        (const __attribute__((address_space(1))) void*)g,
        (__attribute__((address_space(3))) void*)l, 16, 0, 0);
}

// Pack weights for wave-uniform access: wp[g][c][j] = w[(g*8+j)*64 + c]
// g = out-channel group (one per wave), c = in channel, j = 0..7.
__global__ __launch_bounds__(256) void pack_w_kernel(
    const float* __restrict__ w, float* __restrict__ wp) {
    int i = blockIdx.x * 256 + threadIdx.x;   // 0..4095
    int o = i >> 6, c = i & 63;
    wp[(o >> 3) * 512 + c * 8 + (o & 7)] = w[i];
}

// out[b,o,h,w] = sum_c W[o][c] * x[b,c,h-1,w] + bias[o]   (h==0 -> bias only)
// Block: 512 threads = 8 waves. Wave wv owns out-channels wv*8..wv*8+7
// (wave-uniform -> weight loads are broadcast, no LDS traffic for weights).
// Each lane owns 4 pixels. Hot loop per channel: 1 ds_read_b128 + 2 uniform
// weight loads + 32 FMA.
template <bool PACKED>
__global__ __launch_bounds__(512, 4) void shift_pw_kernel(
    const float* __restrict__ x,
    const float* __restrict__ wsrc,   // PACKED ? wp[g][c][8] : W[o][c]
    const float* __restrict__ bias,
    float* __restrict__ out) {

    __shared__ float xs[C_][TP];   // 64 KiB: x tile (row h-1), all 64 channels

    const int tid  = threadIdx.x;
    const int lane = tid & 63;
    const int wv   = tid >> 6;          // 0..7

    int blk = blockIdx.x;
    const int wblk = blk & (NBW - 1);
    blk >>= 1;                          // / NBW
    const int h = blk & (H_ - 1);
    const int b = blk >> 9;             // / H_
    const int w0 = wblk * TP;

    float* xsf = &xs[0][0];

    // ---- stage x row (h-1): each wave loads 8 channel-rows of 1KB ----
    if (h > 0) {
        const float* src = x + ((size_t)b * C_) * HW_ + (size_t)(h - 1) * W_ + w0 + lane * 4;
        #pragma unroll
        for (int p = 0; p < 8; ++p) {
            int c = p * 8 + wv;                        // wave-uniform
            load_lds16(src + (size_t)c * HW_, xsf + c * TP);
        }
    } else {
        float4 z = make_float4(0.f, 0.f, 0.f, 0.f);
        #pragma unroll
        for (int r = 0; r < 8; ++r)
            ((float4*)xsf)[r * 512 + tid] = z;
    }

    // ---- wave-uniform out-channel group ----
    const int wvu = __builtin_amdgcn_readfirstlane(wv);
    const int ob  = wvu * 8;

    float acc[8][4];
    #pragma unroll
    for (int oo = 0; oo < 8; ++oo) {
        float bv = bias[ob + oo];                      // broadcast load
        acc[oo][0] = bv; acc[oo][1] = bv; acc[oo][2] = bv; acc[oo][3] = bv;
    }

    __syncthreads();   // drains global_load_lds + LDS writes

    const int px = lane * 4;

    if constexpr (PACKED) {
        const float* wg = wsrc + wvu * 512;            // this wave's 16KB-resident slice
        #pragma unroll 8
        for (int c = 0; c < C_; ++c) {
            const float4 xv = *(const float4*)&xs[c][px];      // only LDS read in loop
            const float4 wa = *(const float4*)(wg + c * 8);    // uniform -> broadcast
            const float4 wb = *(const float4*)(wg + c * 8 + 4);
            const float xr[4] = {xv.x, xv.y, xv.z, xv.w};
            const float wr[8] = {wa.x, wa.y, wa.z, wa.w, wb.x, wb.y, wb.z, wb.w};
            #pragma unroll
            for (int oo = 0; oo < 8; ++oo)
                #pragma unroll
                for (int j = 0; j < 4; ++j)
                    acc[oo][j] = fmaf(wr[oo], xr[j], acc[oo][j]);
        }
    } else {
        // fallback (no workspace): uniform strided scalar weight loads
        #pragma unroll 8
        for (int c = 0; c < C_; ++c) {
            const float4 xv = *(const float4*)&xs[c][px];
            const float xr[4] = {xv.x, xv.y, xv.z, xv.w};
            #pragma unroll
            for (int oo = 0; oo < 8; ++oo) {
                float wv_ = wsrc[(ob + oo) * C_ + c];           // uniform address
                #pragma unroll
                for (int j = 0; j < 4; ++j)
                    acc[oo][j] = fmaf(wv_, xr[j], acc[oo][j]);
            }
        }
    }

    // ---- coalesced float4 stores: per oo, wave writes 1KB contiguous ----
    float* dst = out + ((size_t)b * C_ + ob) * HW_ + (size_t)h * W_ + w0 + px;
    #pragma unroll
    for (int oo = 0; oo < 8; ++oo) {
        *(float4*)(dst + (size_t)oo * HW_) =
            make_float4(acc[oo][0], acc[oo][1], acc[oo][2], acc[oo][3]);
    }
}

extern "C" void kernel_launch(void* const* d_in, const int* in_sizes, int n_in,
                              void* d_out, int out_size, void* d_ws, size_t ws_size,
                              hipStream_t stream) {
    const float* x    = (const float*)d_in[0];   // [4,64,512,512]
    const float* w    = (const float*)d_in[1];   // [64,64]
    const float* bias = (const float*)d_in[2];   // [64]
    float* out = (float*)d_out;

    const int grid = B_ * H_ * NBW;              // 4096 blocks

    if (ws_size >= C_ * C_ * sizeof(float)) {
        float* wp = (float*)d_ws;
        pack_w_kernel<<<16, 256, 0, stream>>>(w, wp);
        shift_pw_kernel<true><<<grid, 512, 0, stream>>>(x, wp, bias, out);
    } else {
        shift_pw_kernel<false><<<grid, 512, 0, stream>>>(x, w, bias, out);
    }
}